// Round 3
// baseline (1591.238 us; speedup 1.0000x reference)
//
#include <hip/hip_runtime.h>
#include <math.h>

#define WSZ 11
#define SH 128            // y-strip height
#define SW 256            // x-strip width
#define NT 320            // 5 waves: one field each
#define STEPS (SH + 10)   // 138

struct GW { float g[WSZ]; };

struct Win { float f3; float4 w1, w2, w3; float f16; };

__device__ __forceinline__ void load_win(const float* __restrict__ rowp, int Jb, Win& W) {
  const int i0 = 4 * Jb + 3;
  W.f3 = rowp[i0 < 0 ? 0 : i0];
  const int j1 = Jb + 1;
  W.w1 = *(const float4*)(rowp + 4 * (j1 < 0 ? 0 : j1));
  W.w2 = *(const float4*)(rowp + 4 * (Jb + 2));
  const int j3 = Jb + 3;
  W.w3 = *(const float4*)(rowp + 4 * (j3 > 127 ? 127 : j3));
  const int i4 = 4 * (Jb + 4);
  W.f16 = rowp[i4 > 511 ? 511 : i4];
}

__device__ __forceinline__ void win_fix(int Jb, Win& W) {
  if (4 * Jb + 3 < 0) W.f3 = 0.f;
  if (Jb + 1 < 0) W.w1 = make_float4(0.f, 0.f, 0.f, 0.f);
  if (Jb + 3 > 127) W.w3 = make_float4(0.f, 0.f, 0.f, 0.f);
  if (4 * (Jb + 4) > 511) W.f16 = 0.f;
}

__device__ __forceinline__ void win_vals(const Win& W, float v[14]) {
  v[0] = W.f3;
  v[1] = W.w1.x;  v[2] = W.w1.y;  v[3] = W.w1.z;  v[4] = W.w1.w;
  v[5] = W.w2.x;  v[6] = W.w2.y;  v[7] = W.w2.z;  v[8] = W.w2.w;
  v[9] = W.w3.x;  v[10] = W.w3.y; v[11] = W.w3.z; v[12] = W.w3.w;
  v[13] = W.f16;
}

__device__ __forceinline__ float4 blur_h(const float v[14], const GW& g) {
  float4 h = make_float4(0.f, 0.f, 0.f, 0.f);
#pragma unroll
  for (int k = 0; k < WSZ; k++) {
    const float gk = g.g[k];
    h.x = fmaf(gk, v[k],     h.x);
    h.y = fmaf(gk, v[k + 1], h.y);
    h.z = fmaf(gk, v[k + 2], h.z);
    h.w = fmaf(gk, v[k + 3], h.w);
  }
  return h;
}

__device__ __forceinline__ float4 calc_h(int wv, int Jb, Win& WA, Win& WB, const GW& g) {
  float v[14];
  if (wv == 0) { win_fix(Jb, WA); win_vals(WA, v); }
  else if (wv == 1) { win_fix(Jb, WB); win_vals(WB, v); }
  else if (wv == 2) {
    win_fix(Jb, WA); win_vals(WA, v);
#pragma unroll
    for (int t = 0; t < 14; t++) v[t] *= v[t];
  } else if (wv == 3) {
    win_fix(Jb, WB); win_vals(WB, v);
#pragma unroll
    for (int t = 0; t < 14; t++) v[t] *= v[t];
  } else {
    win_fix(Jb, WA); win_fix(Jb, WB);
    float u[14];
    win_vals(WA, v); win_vals(WB, u);
#pragma unroll
    for (int t = 0; t < 14; t++) v[t] *= u[t];
  }
  return blur_h(v, g);
}

__device__ __forceinline__ float ssim_px(float m1, float m2, float m11,
                                         float m22, float m12) {
  const float C1 = 0.0001f, C2 = 0.0009f;
  const float mu1s = m1 * m1, mu2s = m2 * m2, mu12 = m1 * m2;
  const float num = (2.f * mu12 + C1) * (2.f * (m12 - mu12) + C2);
  const float den = (mu1s + mu2s + C1) * ((m11 - mu1s) + (m22 - mu2s) + C2);
  return num * __builtin_amdgcn_rcpf(den);
}

// One row-step. SMOD_ = s % 11 (compile-time), JMIN_ = warm-up gate (compile-time).
#define STEP(SMOD_, JMIN_, S_)                                                 \
  {                                                                            \
    const int s_ = (S_);                                                       \
    const int rld = y0 - 4 + s_; /* row to load; current hcur is row rld-1 */  \
    const bool ldok = (rld >= 0) & (rld < 512);                                \
    Win WA, WB;                                                                \
    if (ldok) {                                                                \
      if (wv == 0 || wv == 2 || wv == 4) load_win(p1 + rld * 512, Jb, WA);     \
      if (wv == 1 || wv == 3 || wv == 4) load_win(p2 + rld * 512, Jb, WB);     \
    }                                                                          \
    _Pragma("unroll")                                                          \
    for (int j = (JMIN_); j < 11; ++j) {                                       \
      const int sl = ((SMOD_) + 1 + j) % 11;                                   \
      const float gw = g.g[10 - j];                                            \
      acc[sl].x = fmaf(gw, hcur.x, acc[sl].x);                                 \
      acc[sl].y = fmaf(gw, hcur.y, acc[sl].y);                                 \
      acc[sl].z = fmaf(gw, hcur.z, acc[sl].z);                                 \
      acc[sl].w = fmaf(gw, hcur.w, acc[sl].w);                                 \
    }                                                                          \
    const int par = s_ & 1;                                                    \
    if (s_ >= 10) {                                                            \
      const int so = ((SMOD_) + 1) % 11;                                       \
      comm[par][wv][lane] = acc[so];                                           \
      acc[so] = make_float4(0.f, 0.f, 0.f, 0.f);                               \
    }                                                                          \
    __syncthreads();                                                           \
    if (s_ >= 10 && wv == (s_ & 3)) {                                          \
      const float4 c0 = comm[par][0][lane];                                    \
      const float4 c1 = comm[par][1][lane];                                    \
      const float4 c2 = comm[par][2][lane];                                    \
      const float4 c3 = comm[par][3][lane];                                    \
      const float4 c4 = comm[par][4][lane];                                    \
      ssimAcc += ssim_px(c0.x, c1.x, c2.x, c3.x, c4.x);                        \
      ssimAcc += ssim_px(c0.y, c1.y, c2.y, c3.y, c4.y);                        \
      ssimAcc += ssim_px(c0.z, c1.z, c2.z, c3.z, c4.z);                        \
      ssimAcc += ssim_px(c0.w, c1.w, c2.w, c3.w, c4.w);                        \
    }                                                                          \
    if (ldok) hcur = calc_h(wv, Jb, WA, WB, g);                                \
    else hcur = make_float4(0.f, 0.f, 0.f, 0.f);                               \
  }

__global__ __launch_bounds__(NT, 4) void ssim_main_kernel(
    const float* __restrict__ img1, const float* __restrict__ img2,
    float* __restrict__ partials, GW g)
{
  __shared__ float4 comm[2][5][64];
  __shared__ float sred[NT / 64];

  const int tid = threadIdx.x;
  const int wv = tid >> 6;     // wave -> field: 0:a 1:b 2:aa 3:bb 4:ab
  const int lane = tid & 63;

  int b = blockIdx.x;
  const int xs = b & 1;  b >>= 1;
  const int ys = b & 3;  b >>= 2;
  const int plane = b;

  const int x0 = xs * SW;
  const int y0 = ys * SH;
  const int Jb = (x0 >> 2) + lane - 2;   // window base float4 index

  const float* __restrict__ p1 = img1 + (size_t)plane * 262144;
  const float* __restrict__ p2 = img2 + (size_t)plane * 262144;

  float4 acc[11];
#pragma unroll
  for (int i = 0; i < 11; i++) acc[i] = make_float4(0.f, 0.f, 0.f, 0.f);
  float ssimAcc = 0.f;
  float4 hcur;

  // prologue: h for row y0-5
  {
    const int r0 = y0 - 5;
    if (r0 >= 0) {
      Win WA, WB;
      if (wv == 0 || wv == 2 || wv == 4) load_win(p1 + r0 * 512, Jb, WA);
      if (wv == 1 || wv == 3 || wv == 4) load_win(p2 + r0 * 512, Jb, WB);
      hcur = calc_h(wv, Jb, WA, WB, g);
    } else hcur = make_float4(0.f, 0.f, 0.f, 0.f);
  }

  // warm-up: s = 0..10, gate j >= 10-s so pre-strip outputs never pollute slots
  STEP(0, 10, 0)  STEP(1, 9, 1)  STEP(2, 8, 2)  STEP(3, 7, 3)
  STEP(4, 6, 4)   STEP(5, 5, 5)  STEP(6, 4, 6)  STEP(7, 3, 7)
  STEP(8, 2, 8)   STEP(9, 1, 9)  STEP(10, 0, 10)

  // main: s = 11..131 in chunks of 11 (sc multiple of 11 -> s%11 == u, static)
  for (int sc = 11; sc <= 121; sc += 11) {
    STEP(0, 0, sc + 0)  STEP(1, 0, sc + 1)  STEP(2, 0, sc + 2)
    STEP(3, 0, sc + 3)  STEP(4, 0, sc + 4)  STEP(5, 0, sc + 5)
    STEP(6, 0, sc + 6)  STEP(7, 0, sc + 7)  STEP(8, 0, sc + 8)
    STEP(9, 0, sc + 9)  STEP(10, 0, sc + 10)
  }

  // tail: s = 132..137  (132 % 11 == 0)
  STEP(0, 0, 132) STEP(1, 0, 133) STEP(2, 0, 134)
  STEP(3, 0, 135) STEP(4, 0, 136) STEP(5, 0, 137)

  // block reduction
  for (int off = 32; off > 0; off >>= 1)
    ssimAcc += __shfl_down(ssimAcc, off, 64);
  if (lane == 0) sred[wv] = ssimAcc;
  __syncthreads();
  if (tid == 0) {
    float s = 0.f;
#pragma unroll
    for (int i = 0; i < NT / 64; i++) s += sred[i];
    partials[blockIdx.x] = s;
  }
}

__global__ __launch_bounds__(256) void ssim_final_kernel(
    const float* __restrict__ partials, float* __restrict__ out,
    int n, double invN)
{
  __shared__ double sred[4];
  const int tid = threadIdx.x;
  double s = 0.0;
  for (int i = tid; i < n; i += 256) s += (double)partials[i];
  for (int off = 32; off > 0; off >>= 1)
    s += __shfl_down(s, off, 64);
  if ((tid & 63) == 0) sred[tid >> 6] = s;
  __syncthreads();
  if (tid == 0) {
    double tot = 0.0;
#pragma unroll
    for (int i = 0; i < 4; i++) tot += sred[i];
    out[0] = (float)(1.0 - tot * invN);
  }
}

extern "C" void kernel_launch(void* const* d_in, const int* in_sizes, int n_in,
                              void* d_out, int out_size, void* d_ws, size_t ws_size,
                              hipStream_t stream) {
  const float* img1 = (const float*)d_in[0];
  const float* img2 = (const float*)d_in[1];
  float* out = (float*)d_out;
  float* partials = (float*)d_ws;

  const int planes = in_sizes[0] / (512 * 512);   // 96
  const int nBlocks = planes * 2 * (512 / SH);    // 96 * 8 = 768

  GW w;
  {
    double g[WSZ], sum = 0.0;
    for (int i = 0; i < WSZ; i++) {
      const double x = (double)(i - WSZ / 2);
      g[i] = exp(-(x * x) / (2.0 * 1.5 * 1.5));
      sum += g[i];
    }
    for (int i = 0; i < WSZ; i++) w.g[i] = (float)(g[i] / sum);
  }

  const double invN = 1.0 / (double)in_sizes[0];

  ssim_main_kernel<<<nBlocks, NT, 0, stream>>>(img1, img2, partials, w);
  ssim_final_kernel<<<1, 256, 0, stream>>>(partials, out, nBlocks, invN);
}

// Round 4
// 170.032 us; speedup vs baseline: 9.3585x; 9.3585x over previous
//
#include <hip/hip_runtime.h>
#include <math.h>

#define WSZ 11
#define TX 64
#define TY 32
#define IN_H 42           // TY + 10
#define SIP 68            // si row stride (floats): rows 2 apart -> 8-bank stagger
#define NTHREADS 256
#define NBLOCKS 2048

struct GW { float g[WSZ]; };

struct Win { float f3; float4 w1, w2, w3; float f16; };

__device__ __forceinline__ void load_win(const float* __restrict__ rowp, int Jb, Win& W) {
  const int i0 = 4 * Jb + 3;
  W.f3 = rowp[i0 < 0 ? 0 : i0];
  const int j1 = Jb + 1;
  W.w1 = *(const float4*)(rowp + 4 * (j1 < 0 ? 0 : j1));
  W.w2 = *(const float4*)(rowp + 4 * (Jb + 2));
  const int j3 = Jb + 3;
  W.w3 = *(const float4*)(rowp + 4 * (j3 > 127 ? 127 : j3));
  const int i4 = 4 * (Jb + 4);
  W.f16 = rowp[i4 > 511 ? 511 : i4];
}

__device__ __forceinline__ void win_fix(int Jb, Win& W) {
  if (4 * Jb + 3 < 0) W.f3 = 0.f;
  if (Jb + 1 < 0) W.w1 = make_float4(0.f, 0.f, 0.f, 0.f);
  if (Jb + 3 > 127) W.w3 = make_float4(0.f, 0.f, 0.f, 0.f);
  if (4 * (Jb + 4) > 511) W.f16 = 0.f;
}

__device__ __forceinline__ void win_vals(const Win& W, float v[14]) {
  v[0] = W.f3;
  v[1] = W.w1.x;  v[2] = W.w1.y;  v[3] = W.w1.z;  v[4] = W.w1.w;
  v[5] = W.w2.x;  v[6] = W.w2.y;  v[7] = W.w2.z;  v[8] = W.w2.w;
  v[9] = W.w3.x;  v[10] = W.w3.y; v[11] = W.w3.z; v[12] = W.w3.w;
  v[13] = W.f16;
}

__device__ __forceinline__ void fma4(float4& a, float g, const float4& v) {
  a.x = fmaf(g, v.x, a.x); a.y = fmaf(g, v.y, a.y);
  a.z = fmaf(g, v.z, a.z); a.w = fmaf(g, v.w, a.w);
}

__device__ __forceinline__ float ssim_px(float m1, float m2, float m11,
                                         float m22, float m12) {
  const float C1 = 0.0001f, C2 = 0.0009f;
  const float mu1s = m1 * m1, mu2s = m2 * m2, mu12 = m1 * m2;
  const float num = (2.f * mu12 + C1) * (2.f * (m12 - mu12) + C2);
  const float den = (mu1s + mu2s + C1) * ((m11 - mu1s) + (m22 - mu2s) + C2);
  return num * __builtin_amdgcn_rcpf(den);
}

__global__ __launch_bounds__(NTHREADS, 2) void ssim_main_kernel(
    const float* __restrict__ img1, const float* __restrict__ img2,
    float* __restrict__ partials, GW w, int nTiles)
{
  __shared__ __align__(16) float si[5][IN_H][SIP];  // 57,120 B
  __shared__ float sred[NTHREADS / 64];

  const int tid = threadIdx.x;
  float accSum = 0.f;

  for (int tile = blockIdx.x; tile < nTiles; tile += gridDim.x) {
    int t = tile;
    const int tx = t & 7;   t >>= 3;   // 512/TX = 8
    const int ty = t & 15;  t >>= 4;   // 512/TY = 16
    const float* __restrict__ p1 = img1 + (size_t)t * 262144;
    const float* __restrict__ p2 = img2 + (size_t)t * 262144;
    const int gy0 = ty * TY - 5;

    // ---- horizontal pass: windows straight from global (L1), 4 px/item ----
    // items: 42 rows x 16 j-groups = 672
    for (int i = tid; i < IN_H * 16; i += NTHREADS) {
      const int r = i >> 4, j = i & 15;
      const int gy = gy0 + r;
      if (gy >= 0 && gy < 512) {
        const int Jb = tx * 16 + j - 2;
        Win WA, WB;
        load_win(p1 + (size_t)gy * 512, Jb, WA);
        load_win(p2 + (size_t)gy * 512, Jb, WB);
        win_fix(Jb, WA); win_fix(Jb, WB);
        float a[14], b[14];
        win_vals(WA, a); win_vals(WB, b);
        float aa[14], bb[14], ab[14];
#pragma unroll
        for (int q = 0; q < 14; q++) {
          aa[q] = a[q] * a[q]; bb[q] = b[q] * b[q]; ab[q] = a[q] * b[q];
        }
        float m1[4] = {0, 0, 0, 0}, m2[4] = {0, 0, 0, 0}, m11[4] = {0, 0, 0, 0},
              m22[4] = {0, 0, 0, 0}, m12[4] = {0, 0, 0, 0};
#pragma unroll
        for (int k = 0; k < WSZ; k++) {
          const float g = w.g[k];
#pragma unroll
          for (int x = 0; x < 4; x++) {
            m1[x]  = fmaf(g, a[x + k],  m1[x]);
            m2[x]  = fmaf(g, b[x + k],  m2[x]);
            m11[x] = fmaf(g, aa[x + k], m11[x]);
            m22[x] = fmaf(g, bb[x + k], m22[x]);
            m12[x] = fmaf(g, ab[x + k], m12[x]);
          }
        }
        *(float4*)&si[0][r][4 * j] = make_float4(m1[0], m1[1], m1[2], m1[3]);
        *(float4*)&si[1][r][4 * j] = make_float4(m2[0], m2[1], m2[2], m2[3]);
        *(float4*)&si[2][r][4 * j] = make_float4(m11[0], m11[1], m11[2], m11[3]);
        *(float4*)&si[3][r][4 * j] = make_float4(m22[0], m22[1], m22[2], m22[3]);
        *(float4*)&si[4][r][4 * j] = make_float4(m12[0], m12[1], m12[2], m12[3]);
      } else {
        const float4 z = make_float4(0.f, 0.f, 0.f, 0.f);
#pragma unroll
        for (int f = 0; f < 5; f++) *(float4*)&si[f][r][4 * j] = z;
      }
    }
    __syncthreads();

    // ---- vertical pass + SSIM: 4x x 2y per thread (256 items) ----
    {
      const int yi = tid >> 4, j = tid & 15;
      const int y0 = 2 * yi;
      float4 acc0[5], acc1[5];
#pragma unroll
      for (int f = 0; f < 5; f++) {
        acc0[f] = make_float4(0.f, 0.f, 0.f, 0.f);
        acc1[f] = make_float4(0.f, 0.f, 0.f, 0.f);
      }
#pragma unroll
      for (int k = 0; k < WSZ + 1; k++) {
        const int rr = y0 + k;
#pragma unroll
        for (int f = 0; f < 5; f++) {
          const float4 v = *(const float4*)&si[f][rr][4 * j];
          if (k < WSZ) fma4(acc0[f], w.g[k], v);
          if (k >= 1)  fma4(acc1[f], w.g[k - 1], v);
        }
      }
      accSum += ssim_px(acc0[0].x, acc0[1].x, acc0[2].x, acc0[3].x, acc0[4].x);
      accSum += ssim_px(acc0[0].y, acc0[1].y, acc0[2].y, acc0[3].y, acc0[4].y);
      accSum += ssim_px(acc0[0].z, acc0[1].z, acc0[2].z, acc0[3].z, acc0[4].z);
      accSum += ssim_px(acc0[0].w, acc0[1].w, acc0[2].w, acc0[3].w, acc0[4].w);
      accSum += ssim_px(acc1[0].x, acc1[1].x, acc1[2].x, acc1[3].x, acc1[4].x);
      accSum += ssim_px(acc1[0].y, acc1[1].y, acc1[2].y, acc1[3].y, acc1[4].y);
      accSum += ssim_px(acc1[0].z, acc1[1].z, acc1[2].z, acc1[3].z, acc1[4].z);
      accSum += ssim_px(acc1[0].w, acc1[1].w, acc1[2].w, acc1[3].w, acc1[4].w);
    }
    __syncthreads();  // protect si before next tile overwrites
  }

  // ---- block reduction ----
  for (int off = 32; off > 0; off >>= 1)
    accSum += __shfl_down(accSum, off, 64);
  if ((tid & 63) == 0) sred[tid >> 6] = accSum;
  __syncthreads();
  if (tid == 0) {
    float s = 0.f;
#pragma unroll
    for (int i = 0; i < NTHREADS / 64; i++) s += sred[i];
    partials[blockIdx.x] = s;
  }
}

__global__ __launch_bounds__(256) void ssim_final_kernel(
    const float* __restrict__ partials, float* __restrict__ out,
    int n, double invN)
{
  __shared__ double sred[4];
  const int tid = threadIdx.x;
  double s = 0.0;
  for (int i = tid; i < n; i += 256) s += (double)partials[i];
  for (int off = 32; off > 0; off >>= 1)
    s += __shfl_down(s, off, 64);
  if ((tid & 63) == 0) sred[tid >> 6] = s;
  __syncthreads();
  if (tid == 0) {
    double tot = 0.0;
#pragma unroll
    for (int i = 0; i < 4; i++) tot += sred[i];
    out[0] = (float)(1.0 - tot * invN);
  }
}

extern "C" void kernel_launch(void* const* d_in, const int* in_sizes, int n_in,
                              void* d_out, int out_size, void* d_ws, size_t ws_size,
                              hipStream_t stream) {
  const float* img1 = (const float*)d_in[0];
  const float* img2 = (const float*)d_in[1];
  float* out = (float*)d_out;
  float* partials = (float*)d_ws;

  const int planes = in_sizes[0] / (512 * 512);     // 96
  const int nTiles = planes * 8 * 16;               // 12288

  GW w;
  {
    double g[WSZ], sum = 0.0;
    for (int i = 0; i < WSZ; i++) {
      const double x = (double)(i - WSZ / 2);
      g[i] = exp(-(x * x) / (2.0 * 1.5 * 1.5));
      sum += g[i];
    }
    for (int i = 0; i < WSZ; i++) w.g[i] = (float)(g[i] / sum);
  }

  const double invN = 1.0 / (double)in_sizes[0];

  ssim_main_kernel<<<NBLOCKS, NTHREADS, 0, stream>>>(img1, img2, partials, w, nTiles);
  ssim_final_kernel<<<1, 256, 0, stream>>>(partials, out, NBLOCKS, invN);
}